// Round 15
// baseline (34.548 us; speedup 1.0000x reference)
//
#include <hip/hip_runtime.h>
#include <math.h>

#define W 512
#define H 512
#define IMG (W * H)
#define LSTRIDE 52        // LDS row stride in floats (window 48 cols + pad)
#define LWORDS 4096       // 16 chunks * 256 floats >= 76*52 = 3952

// ---------------- compile-time operator tables ----------------
// 1D composed second-difference D = diff(diff(.)) from the reference.
__host__ __device__ constexpr double dcoefd(int i, int j) {
    if (i == 0) return j == 0 ? 0.5 : j == 1 ? -1.0 : j == 2 ? 0.5 : 0.0;
    if (i == 1) return j == 0 ? 0.5 : j == 1 ? -0.75 : j == 3 ? 0.25 : 0.0;
    return j == i - 2 ? 0.25 : j == i ? -0.5 : j == i + 2 ? 0.25 : 0.0;
}

// Ghost-cell coefficients: u_{-k} = sum_j g[k][j]*u_j makes the PURE stencils
// of D, D^2, D^3 reproduce the boundary-aware operator exactly (validated
// rounds 5-14: absmax identical to explicit-boundary versions).
struct GhostT {
    float g[7][8];
    constexpr GhostT() : g{} {
        double v0[8] = {}, v1[8] = {}, v2[8] = {}, w0[8] = {}, w1r[8] = {}, w2r[8] = {};
        for (int j = 0; j < 8; ++j) { v0[j] = dcoefd(0, j); v1[j] = dcoefd(1, j); v2[j] = dcoefd(2, j); }
        for (int j = 0; j < 8; ++j) {
            double s0 = 0, s1 = 0, s2 = 0;
            for (int k = 0; k < 10; ++k) {
                s0 += dcoefd(0, k) * dcoefd(k, j);
                s1 += dcoefd(1, k) * dcoefd(k, j);
                s2 += dcoefd(2, k) * dcoefd(k, j);
            }
            w0[j] = s0; w1r[j] = s1; w2r[j] = s2;
        }
        double um1[8] = {}, um2[8] = {}, um3[8] = {}, um4[8] = {}, um5[8] = {}, um6[8] = {};
        double vm1[8] = {}, vm2[8] = {}, vm3[8] = {}, vm4[8] = {}, wm1[8] = {}, wm2[8] = {};
        for (int j = 0; j < 8; ++j) {
            um1[j] = 2.0 * (j == 0) - (j == 1);
            um2[j] = 4.0 * (j == 0) - 4.0 * (j == 1) + (j == 2);
            vm1[j] = 2 * v0[j] - v1[j];
            vm2[j] = 4 * v0[j] - 4 * v1[j] + v2[j];
            wm1[j] = 2 * w0[j] - w1r[j];
            wm2[j] = 4 * w0[j] - 4 * w1r[j] + w2r[j];
        }
        for (int j = 0; j < 8; ++j) {
            um3[j] = 4 * vm1[j] + 2 * um1[j] - (j == 1);
            um4[j] = 4 * vm2[j] + 2 * um2[j] - (j == 0);
            vm3[j] = 4 * wm1[j] + 2 * vm1[j] - v1[j];
            vm4[j] = 4 * wm2[j] + 2 * vm2[j] - v0[j];
        }
        for (int j = 0; j < 8; ++j) {
            um5[j] = 4 * vm3[j] + 2 * um3[j] - um1[j];
            um6[j] = 4 * vm4[j] + 2 * um4[j] - um2[j];
        }
        for (int j = 0; j < 8; ++j) {
            g[1][j] = (float)um1[j]; g[2][j] = (float)um2[j]; g[3][j] = (float)um3[j];
            g[4][j] = (float)um4[j]; g[5][j] = (float)um5[j]; g[6][j] = (float)um6[j];
        }
    }
};
constexpr GhostT GH{};

__device__ __forceinline__ float4 ld4(const float* p) {
    return *reinterpret_cast<const float4*>(p);
}
__device__ __forceinline__ float rfl(float x) {
    return __int_as_float(__builtin_amdgcn_readfirstlane(__float_as_int(x)));
}

struct Uni {
    float k1, k2, k3, m1, m2, n1;                               // x-side M consts
    float wy1a, wy1b, wy2a, wy2b, wy2c, wy3a, wy3b, wy3c, wy3d; // interior y-weights
    float am, iam;                                              // sigmoid mix, 1/am
};

// One trimmed pure row read from LDS, register-lean pair-sum form.
template<int CLS, int RI>
__device__ __forceinline__ void row_lds(const Uni& U, const float* __restrict__ lbase,
                                        float acc[4][4]) {
    const float* rowp = lbase + 2 * RI * LSTRIDE;
    float u0a[4], t1a[4], t2a[4], t3a[4];
    if (CLS == 0) {
        const float4 m2 = ld4(rowp + 8);
        u0a[0] = m2.x; u0a[1] = m2.y; u0a[2] = m2.z; u0a[3] = m2.w;
    } else if (CLS <= 2) {
        const float4 m1 = ld4(rowp + 4);
        const float4 m2 = ld4(rowp + 8);
        const float4 m3 = ld4(rowp + 12);
        u0a[0] = m2.x; u0a[1] = m2.y; u0a[2] = m2.z; u0a[3] = m2.w;
        t1a[0] = m1.z + m2.z; t1a[1] = m1.w + m2.w;
        t1a[2] = m2.x + m3.x; t1a[3] = m2.y + m3.y;
        t2a[0] = m1.x + m3.x; t2a[1] = m1.y + m3.y;
        t2a[2] = m1.z + m3.z; t2a[3] = m1.w + m3.w;
    } else {
        const float4 m0 = ld4(rowp);
        const float4 m4 = ld4(rowp + 16);
        const float4 m1 = ld4(rowp + 4);
        const float4 m3 = ld4(rowp + 12);
        t3a[0] = m0.z + m3.z; t3a[1] = m0.w + m3.w;     // rb[2+j] + rb[14+j]
        t3a[2] = m1.x + m4.x; t3a[3] = m1.y + m4.y;
        t2a[0] = m1.x + m3.x; t2a[1] = m1.y + m3.y;     // rb[4+j] + rb[12+j]
        t2a[2] = m1.z + m3.z; t2a[3] = m1.w + m3.w;
        const float4 m2 = ld4(rowp + 8);
        t1a[0] = m1.z + m2.z; t1a[1] = m1.w + m2.w;     // rb[6+j] + rb[10+j]
        t1a[2] = m2.x + m3.x; t1a[3] = m2.y + m3.y;
        u0a[0] = m2.x; u0a[1] = m2.y; u0a[2] = m2.z; u0a[3] = m2.w;
    }

    #pragma unroll
    for (int j = 0; j < 4; ++j) {
        const float u0 = u0a[j];
        const float M3v = 120.f * u0;
        float M2v = 0.f, M1v = 0.f, M0v = 0.f;
        if (CLS >= 1) {
            const float X1 = fmaf(0.25f, t1a[j], -0.5f * u0);
            M2v = fmaf(U.n1, X1, 45.f * u0);
            if (CLS >= 2) {
                const float X2 = fmaf(0.0625f, t2a[j], fmaf(-0.25f, t1a[j], 0.375f * u0));
                M1v = fmaf(U.m1, X1, fmaf(U.m2, X2, 10.f * u0));
                if (CLS >= 3) {
                    const float X3 = fmaf(1.f/64, t3a[j], fmaf(-6.f/64, t2a[j],
                                      fmaf(15.f/64, t1a[j], (-20.f/64) * u0)));
                    M0v = fmaf(U.k1, X1, fmaf(U.k2, X2, U.k3 * X3));
                }
            }
        }
        #pragma unroll
        for (int k = 0; k < 4; ++k) {
            const int dq = RI - 3 - k;
            const int ad = dq < 0 ? -dq : dq;
            if (ad > 3) continue;
            float a = acc[k][j];
            if (ad == 0) {
                a = fmaf(U.iam, u0, a);       // fold u/am into acc
                a += M0v;
                a = fmaf(U.wy1b, M1v, a);
                a = fmaf(U.wy2c, M2v, a);
                a = fmaf(U.wy3d, M3v, a);
            } else if (ad == 1) {
                a = fmaf(U.wy1a, M1v, a);
                a = fmaf(U.wy2b, M2v, a);
                a = fmaf(U.wy3c, M3v, a);
            } else if (ad == 2) {
                a = fmaf(U.wy2a, M2v, a);
                a = fmaf(U.wy3b, M3v, a);
            } else {
                a = fmaf(U.wy3a, M3v, a);
            }
            acc[k][j] = a;
        }
    }
}

__global__ __launch_bounds__(128) void fused_v15(
        const float* __restrict__ uin, float* __restrict__ outp,
        const float* __restrict__ alpha, const float* __restrict__ beta,
        const float* __restrict__ axp, const float* __restrict__ ayp,
        const float* __restrict__ es) {
    __shared__ float lds0[LWORDS];

    // XCD-chunked swizzle (grid 8192 = 8*1024)
    const unsigned bid = blockIdx.x;
    const unsigned swz = (bid & 7u) * (gridDim.x >> 3) + (bid >> 3);
    const unsigned img  = swz >> 7;          // 128 tiles (8 trow x 16 tcol) per image
    const unsigned tile = swz & 127u;
    const int gx0 = (int)(tile & 15u) << 5;  // 32-col tiles
    const int gy0 = (int)(tile >> 4) << 6;   // 64-row tiles
    const float* __restrict__ p = uin + (size_t)img * IMG;
    float* __restrict__ q = outp + (size_t)img * IMG;

    const int tid = threadIdx.x;
    const int wid = tid >> 6, lane = tid & 63;

    // ---- stage window rows [-6,70) x cols [-8,40) via global_load_lds ----
    for (int t = wid; t < 16; t += 2) {
        int idx = (t << 8) + (lane << 2);
        int row = (int)((unsigned)idx / 52u);
        if (row > 75) row = 75;
        int col = idx - row * 52;
        int gy = gy0 + row - 6;
        gy = gy < 0 ? 0 : (gy > H - 1 ? H - 1 : gy);
        int gx = gx0 + col - 8;
        gx = gx < 0 ? 0 : (gx > W - 4 ? W - 4 : gx);
        const float* src = p + (size_t)gy * W + gx;
        __builtin_amdgcn_global_load_lds(
            (const __attribute__((address_space(1))) void*)src,
            (__attribute__((address_space(3))) void*)&lds0[t << 8],
            16, 0, 0);
    }
    __syncthreads();

    // ---- y-ghost rows for top/bottom tiles (re-read per k, lean regs) ----
    if (gy0 == 0 || gy0 == H - 64) {
        if (tid < 12) {                       // 12 quads cover 48 cols
            const int w0 = tid << 2;
            #pragma unroll
            for (int k = 1; k <= 6; ++k) {
                float4 a = {0.f, 0.f, 0.f, 0.f};
                #pragma unroll
                for (int j = 0; j < 8; ++j) {
                    const float w = GH.g[k][j];
                    if (w != 0.f) {
                        const int srow = (gy0 == 0) ? (6 + j) : (69 - j);
                        const float4 r = ld4(&lds0[srow * LSTRIDE + w0]);
                        a.x = fmaf(w, r.x, a.x); a.y = fmaf(w, r.y, a.y);
                        a.z = fmaf(w, r.z, a.z); a.w = fmaf(w, r.w, a.w);
                    }
                }
                const int drow = (gy0 == 0) ? (6 - k) : (69 + k);
                *reinterpret_cast<float4*>(&lds0[drow * LSTRIDE + w0]) = a;
            }
        }
        __syncthreads();
    }

    // ---- x-ghost cols for left/right tiles (after y-ghosts: exact) ----
    if (gx0 == 0 || gx0 == W - 32) {
        if (tid < 76) {
            float* rp = &lds0[tid * LSTRIDE];
            #pragma unroll
            for (int k = 1; k <= 6; ++k) {
                float s = 0.f;
                #pragma unroll
                for (int j = 0; j < 8; ++j) {
                    const float w = GH.g[k][j];
                    if (w != 0.f) {
                        const float v = (gx0 == 0) ? rp[8 + j] : rp[39 - j];
                        s = fmaf(w, v, s);
                    }
                }
                if (gx0 == 0) rp[8 - k] = s; else rp[39 + k] = s;
            }
        }
        __syncthreads();
    }

    // ---- uniform constants (SGPR via readfirstlane) ----
    const float sx = 0.01f * alpha[0] * axp[0];
    const float sy = 0.01f * beta[0]  * ayp[0];
    Uni U;
    U.k1 = rfl(10.f * sx);  U.k2 = rfl(45.f * sx * sx);  U.k3 = rfl(120.f * sx * sx * sx);
    U.m1 = rfl(90.f * sx);  U.m2 = rfl(360.f * sx * sx); U.n1 = rfl(360.f * sx);
    const float sy2 = sy * sy, sy3 = sy2 * sy;
    U.wy1a = rfl(0.25f * sy);    U.wy1b = rfl(-0.5f * sy);
    U.wy2a = rfl(0.0625f * sy2); U.wy2b = rfl(-0.25f * sy2); U.wy2c = rfl(0.375f * sy2);
    U.wy3a = rfl((1.f/64) * sy3);  U.wy3b = rfl((-6.f/64) * sy3);
    U.wy3c = rfl((15.f/64) * sy3); U.wy3d = rfl((-20.f/64) * sy3);
    const float amv = 1.f / (1.f + expf(-es[0]));
    U.am = rfl(amv); U.iam = rfl(1.f / amv);

    // ---- compute: thread = 4-col quad x 4 same-parity rows, branch-free ----
    const int qc = tid & 7, g = tid >> 3;        // 8 quads x 16 row groups
    const int y0 = ((g >> 1) << 3) + (g & 1);
    const int x0 = qc << 2;
    const float* lbase = &lds0[y0 * LSTRIDE + x0];

    float acc[4][4] = {};
    row_lds<0, 0>(U, lbase, acc);
    row_lds<1, 1>(U, lbase, acc);
    row_lds<2, 2>(U, lbase, acc);
    row_lds<3, 3>(U, lbase, acc);
    row_lds<3, 4>(U, lbase, acc);
    row_lds<3, 5>(U, lbase, acc);
    row_lds<3, 6>(U, lbase, acc);
    row_lds<2, 7>(U, lbase, acc);
    row_lds<1, 8>(U, lbase, acc);
    row_lds<0, 9>(U, lbase, acc);

    // ---- out = am * acc  (acc already contains u/am at the dq==0 row) ----
    #pragma unroll
    for (int k = 0; k < 4; ++k) {
        const int Yo = gy0 + y0 + 2 * k;
        float4 o;
        o.x = U.am * acc[k][0];
        o.y = U.am * acc[k][1];
        o.z = U.am * acc[k][2];
        o.w = U.am * acc[k][3];
        *reinterpret_cast<float4*>(q + (size_t)Yo * W + gx0 + x0) = o;
    }
}

extern "C" void kernel_launch(void* const* d_in, const int* in_sizes, int n_in,
                              void* d_out, int out_size, void* d_ws, size_t ws_size,
                              hipStream_t stream) {
    const float* u     = (const float*)d_in[0];
    const float* alpha = (const float*)d_in[1];
    const float* beta  = (const float*)d_in[2];
    const float* ax    = (const float*)d_in[3];
    const float* ay    = (const float*)d_in[4];
    const float* es    = (const float*)d_in[5];
    float* out = (float*)d_out;

    int nimg = in_sizes[0] / IMG;            // 64 images
    dim3 block(128);
    dim3 grid((unsigned)(nimg * 128));       // 8x16 tiles of 64x32 per image
    fused_v15<<<grid, block, 0, stream>>>(u, out, alpha, beta, ax, ay, es);
}

// Round 17
// 34.128 us; speedup vs baseline: 1.0123x; 1.0123x over previous
//
#include <hip/hip_runtime.h>
#include <math.h>

#define W 512
#define H 512
#define IMG (W * H)
#define LSTRIDE 84        // LDS row stride in floats
#define WWORDS 2560       // private words per wave (28 rows x 84 = 2352 + pad)
#define LWORDS (4 * WWORDS)

// ---------------- compile-time operator tables ----------------
// 1D composed second-difference D = diff(diff(.)) from the reference.
__host__ __device__ constexpr double dcoefd(int i, int j) {
    if (i == 0) return j == 0 ? 0.5 : j == 1 ? -1.0 : j == 2 ? 0.5 : 0.0;
    if (i == 1) return j == 0 ? 0.5 : j == 1 ? -0.75 : j == 3 ? 0.25 : 0.0;
    return j == i - 2 ? 0.25 : j == i ? -0.5 : j == i + 2 ? 0.25 : 0.0;
}

// Ghost-cell coefficients: u_{-k} = sum_j g[k][j]*u_j makes the PURE stencils
// of D, D^2, D^3 reproduce the boundary-aware operator exactly (validated
// rounds 5-15: absmax identical to explicit-boundary versions).
struct GhostT {
    float g[7][8];
    constexpr GhostT() : g{} {
        double v0[8] = {}, v1[8] = {}, v2[8] = {}, w0[8] = {}, w1r[8] = {}, w2r[8] = {};
        for (int j = 0; j < 8; ++j) { v0[j] = dcoefd(0, j); v1[j] = dcoefd(1, j); v2[j] = dcoefd(2, j); }
        for (int j = 0; j < 8; ++j) {
            double s0 = 0, s1 = 0, s2 = 0;
            for (int k = 0; k < 10; ++k) {
                s0 += dcoefd(0, k) * dcoefd(k, j);
                s1 += dcoefd(1, k) * dcoefd(k, j);
                s2 += dcoefd(2, k) * dcoefd(k, j);
            }
            w0[j] = s0; w1r[j] = s1; w2r[j] = s2;
        }
        double um1[8] = {}, um2[8] = {}, um3[8] = {}, um4[8] = {}, um5[8] = {}, um6[8] = {};
        double vm1[8] = {}, vm2[8] = {}, vm3[8] = {}, vm4[8] = {}, wm1[8] = {}, wm2[8] = {};
        for (int j = 0; j < 8; ++j) {
            um1[j] = 2.0 * (j == 0) - (j == 1);
            um2[j] = 4.0 * (j == 0) - 4.0 * (j == 1) + (j == 2);
            vm1[j] = 2 * v0[j] - v1[j];
            vm2[j] = 4 * v0[j] - 4 * v1[j] + v2[j];
            wm1[j] = 2 * w0[j] - w1r[j];
            wm2[j] = 4 * w0[j] - 4 * w1r[j] + w2r[j];
        }
        for (int j = 0; j < 8; ++j) {
            um3[j] = 4 * vm1[j] + 2 * um1[j] - (j == 1);
            um4[j] = 4 * vm2[j] + 2 * um2[j] - (j == 0);
            vm3[j] = 4 * wm1[j] + 2 * vm1[j] - v1[j];
            vm4[j] = 4 * wm2[j] + 2 * vm2[j] - v0[j];
        }
        for (int j = 0; j < 8; ++j) {
            um5[j] = 4 * vm3[j] + 2 * um3[j] - um1[j];
            um6[j] = 4 * vm4[j] + 2 * um4[j] - um2[j];
        }
        for (int j = 0; j < 8; ++j) {
            g[1][j] = (float)um1[j]; g[2][j] = (float)um2[j]; g[3][j] = (float)um3[j];
            g[4][j] = (float)um4[j]; g[5][j] = (float)um5[j]; g[6][j] = (float)um6[j];
        }
    }
};
constexpr GhostT GH{};

__device__ __forceinline__ float4 ld4(const float* p) {
    return *reinterpret_cast<const float4*>(p);
}
__device__ __forceinline__ float rfl(float x) {
    return __int_as_float(__builtin_amdgcn_readfirstlane(__float_as_int(x)));
}

struct Uni {
    float k1, k2, k3, m1, m2, n1;                               // x-side M consts
    float wy1a, wy1b, wy2a, wy2b, wy2c, wy3a, wy3b, wy3c, wy3d; // interior y-weights
    float am, iam;                                              // sigmoid mix, 1/am
};

// One trimmed pure row read from LDS, register-lean pair-sum form (v13).
template<int CLS, int RI>
__device__ __forceinline__ void row_lds(const Uni& U, const float* __restrict__ lbase,
                                        float acc[4][4]) {
    const float* rowp = lbase + 2 * RI * LSTRIDE;
    float u0a[4], t1a[4], t2a[4], t3a[4];
    if (CLS == 0) {
        const float4 m2 = ld4(rowp + 8);
        u0a[0] = m2.x; u0a[1] = m2.y; u0a[2] = m2.z; u0a[3] = m2.w;
    } else if (CLS <= 2) {
        const float4 m1 = ld4(rowp + 4);
        const float4 m2 = ld4(rowp + 8);
        const float4 m3 = ld4(rowp + 12);
        u0a[0] = m2.x; u0a[1] = m2.y; u0a[2] = m2.z; u0a[3] = m2.w;
        t1a[0] = m1.z + m2.z; t1a[1] = m1.w + m2.w;
        t1a[2] = m2.x + m3.x; t1a[3] = m2.y + m3.y;
        t2a[0] = m1.x + m3.x; t2a[1] = m1.y + m3.y;
        t2a[2] = m1.z + m3.z; t2a[3] = m1.w + m3.w;
    } else {
        const float4 m0 = ld4(rowp);
        const float4 m4 = ld4(rowp + 16);
        const float4 m1 = ld4(rowp + 4);
        const float4 m3 = ld4(rowp + 12);
        t3a[0] = m0.z + m3.z; t3a[1] = m0.w + m3.w;     // rb[2+j] + rb[14+j]
        t3a[2] = m1.x + m4.x; t3a[3] = m1.y + m4.y;
        t2a[0] = m1.x + m3.x; t2a[1] = m1.y + m3.y;     // rb[4+j] + rb[12+j]
        t2a[2] = m1.z + m3.z; t2a[3] = m1.w + m3.w;
        const float4 m2 = ld4(rowp + 8);
        t1a[0] = m1.z + m2.z; t1a[1] = m1.w + m2.w;     // rb[6+j] + rb[10+j]
        t1a[2] = m2.x + m3.x; t1a[3] = m2.y + m3.y;
        u0a[0] = m2.x; u0a[1] = m2.y; u0a[2] = m2.z; u0a[3] = m2.w;
    }

    #pragma unroll
    for (int j = 0; j < 4; ++j) {
        const float u0 = u0a[j];
        const float M3v = 120.f * u0;
        float M2v = 0.f, M1v = 0.f, M0v = 0.f;
        if (CLS >= 1) {
            const float X1 = fmaf(0.25f, t1a[j], -0.5f * u0);
            M2v = fmaf(U.n1, X1, 45.f * u0);
            if (CLS >= 2) {
                const float X2 = fmaf(0.0625f, t2a[j], fmaf(-0.25f, t1a[j], 0.375f * u0));
                M1v = fmaf(U.m1, X1, fmaf(U.m2, X2, 10.f * u0));
                if (CLS >= 3) {
                    const float X3 = fmaf(1.f/64, t3a[j], fmaf(-6.f/64, t2a[j],
                                      fmaf(15.f/64, t1a[j], (-20.f/64) * u0)));
                    M0v = fmaf(U.k1, X1, fmaf(U.k2, X2, U.k3 * X3));
                }
            }
        }
        #pragma unroll
        for (int k = 0; k < 4; ++k) {
            const int dq = RI - 3 - k;
            const int ad = dq < 0 ? -dq : dq;
            if (ad > 3) continue;
            float a = acc[k][j];
            if (ad == 0) {
                a = fmaf(U.iam, u0, a);       // fold u/am into acc
                a += M0v;
                a = fmaf(U.wy1b, M1v, a);
                a = fmaf(U.wy2c, M2v, a);
                a = fmaf(U.wy3d, M3v, a);
            } else if (ad == 1) {
                a = fmaf(U.wy1a, M1v, a);
                a = fmaf(U.wy2b, M2v, a);
                a = fmaf(U.wy3c, M3v, a);
            } else if (ad == 2) {
                a = fmaf(U.wy2a, M2v, a);
                a = fmaf(U.wy3b, M3v, a);
            } else {
                a = fmaf(U.wy3a, M3v, a);
            }
            acc[k][j] = a;
        }
    }
}

// Barrier-free, race-free: each wave owns a PRIVATE 2560-word LDS region
// holding its 28-row window (tile rows 16w-6 .. 16w+21). No LDS word is
// touched by two waves; wave-local vmcnt(0) orders DMA vs reads; ghosts are
// produced and consumed by the same wave (program order). Zero __syncthreads.
__global__ __launch_bounds__(256) void fused_v17(
        const float* __restrict__ uin, float* __restrict__ outp,
        const float* __restrict__ alpha, const float* __restrict__ beta,
        const float* __restrict__ axp, const float* __restrict__ ayp,
        const float* __restrict__ es) {
    __shared__ float lds0[LWORDS];

    // XCD-chunked swizzle (grid 4096 = 8*512)
    const unsigned bid = blockIdx.x;
    const unsigned swz = (bid & 7u) * (gridDim.x >> 3) + (bid >> 3);
    const unsigned img  = swz >> 6;
    const unsigned tile = swz & 63u;
    const int gx0 = (int)(tile & 7u) << 6;
    const int gy0 = (int)(tile >> 3) << 6;
    const float* __restrict__ p = uin + (size_t)img * IMG;
    float* __restrict__ q = outp + (size_t)img * IMG;

    const int tid = threadIdx.x;
    const int wid = tid >> 6, lane = tid & 63;
    const int WB = wid * WWORDS;                 // private region base
    const int wrow0 = 16 * wid - 6;              // tile row of local row 0

    // ---- per-wave stage: 10 chunks cover local words [0, 2560) ----
    #pragma unroll
    for (int t = 0; t < 10; ++t) {
        int idx = (t << 8) + (lane << 2);        // local word
        int lr  = (int)((unsigned)idx / 84u);    // local row 0..30
        int col = idx - lr * 84;
        int gy = gy0 + wrow0 + lr;
        gy = gy < 0 ? 0 : (gy > H - 1 ? H - 1 : gy);
        int gx = gx0 + col - 8;
        gx = gx < 0 ? 0 : (gx > W - 4 ? W - 4 : gx);
        const float* src = p + (size_t)gy * W + gx;
        __builtin_amdgcn_global_load_lds(
            (const __attribute__((address_space(1))) void*)src,
            (__attribute__((address_space(3))) void*)&lds0[WB + idx],
            16, 0, 0);
    }
    // Wave-local drain: this wave's loads cover every LDS word it reads.
    asm volatile("s_waitcnt vmcnt(0)" ::: "memory");

    // ---- y-ghost rows (wave-local: producer == consumer wave) ----
    if (gy0 == 0 && wid == 0 && lane < 20) {
        const int w0 = lane << 2;
        #pragma unroll
        for (int k = 1; k <= 6; ++k) {           // ghost local rows 5..0
            float4 a = {0.f, 0.f, 0.f, 0.f};
            #pragma unroll
            for (int j = 0; j < 8; ++j) {
                const float w = GH.g[k][j];
                if (w != 0.f) {
                    const float4 r = ld4(&lds0[WB + (6 + j) * LSTRIDE + w0]);
                    a.x = fmaf(w, r.x, a.x); a.y = fmaf(w, r.y, a.y);
                    a.z = fmaf(w, r.z, a.z); a.w = fmaf(w, r.w, a.w);
                }
            }
            *reinterpret_cast<float4*>(&lds0[WB + (6 - k) * LSTRIDE + w0]) = a;
        }
    }
    if (gy0 == H - 64 && wid == 3 && lane < 20) {
        const int w0 = lane << 2;
        #pragma unroll
        for (int k = 1; k <= 6; ++k) {           // ghost local rows 22..27
            float4 a = {0.f, 0.f, 0.f, 0.f};
            #pragma unroll
            for (int j = 0; j < 8; ++j) {
                const float w = GH.g[k][j];
                if (w != 0.f) {                  // src tile rows 63-j -> local 21-j
                    const float4 r = ld4(&lds0[WB + (21 - j) * LSTRIDE + w0]);
                    a.x = fmaf(w, r.x, a.x); a.y = fmaf(w, r.y, a.y);
                    a.z = fmaf(w, r.z, a.z); a.w = fmaf(w, r.w, a.w);
                }
            }
            *reinterpret_cast<float4*>(&lds0[WB + (21 + k) * LSTRIDE + w0]) = a;
        }
    }

    // ---- x-ghost cols for this wave's own 28 rows (after y-ghosts) ----
    if ((gx0 == 0 || gx0 == W - 64) && lane < 28) {
        float* rp = &lds0[WB + lane * LSTRIDE];
        #pragma unroll
        for (int k = 1; k <= 6; ++k) {
            float s = 0.f;
            #pragma unroll
            for (int j = 0; j < 8; ++j) {
                const float w = GH.g[k][j];
                if (w != 0.f) {
                    const float v = (gx0 == 0) ? rp[8 + j] : rp[71 - j];
                    s = fmaf(w, v, s);
                }
            }
            if (gx0 == 0) rp[8 - k] = s; else rp[71 + k] = s;
        }
    }

    // ---- uniform constants (SGPR via readfirstlane) ----
    const float sx = 0.01f * alpha[0] * axp[0];
    const float sy = 0.01f * beta[0]  * ayp[0];
    Uni U;
    U.k1 = rfl(10.f * sx);  U.k2 = rfl(45.f * sx * sx);  U.k3 = rfl(120.f * sx * sx * sx);
    U.m1 = rfl(90.f * sx);  U.m2 = rfl(360.f * sx * sx); U.n1 = rfl(360.f * sx);
    const float sy2 = sy * sy, sy3 = sy2 * sy;
    U.wy1a = rfl(0.25f * sy);    U.wy1b = rfl(-0.5f * sy);
    U.wy2a = rfl(0.0625f * sy2); U.wy2b = rfl(-0.25f * sy2); U.wy2c = rfl(0.375f * sy2);
    U.wy3a = rfl((1.f/64) * sy3);  U.wy3b = rfl((-6.f/64) * sy3);
    U.wy3c = rfl((15.f/64) * sy3); U.wy3d = rfl((-20.f/64) * sy3);
    const float amv = 1.f / (1.f + expf(-es[0]));
    U.am = rfl(amv); U.iam = rfl(1.f / amv);

    // ---- compute: thread = 4-col quad x 4 same-parity rows, branch-free ----
    // Local output row ly0 in {0,1,8,9}; global output row = gy0+16*wid+ly0+2k.
    const int qc = tid & 15;
    const int gw = (tid >> 4) & 3;
    const int ly0 = ((gw >> 1) << 3) + (gw & 1);
    const int x0 = qc << 2;
    const float* lbase = &lds0[WB + ly0 * LSTRIDE + x0];

    float acc[4][4] = {};
    row_lds<0, 0>(U, lbase, acc);
    row_lds<1, 1>(U, lbase, acc);
    row_lds<2, 2>(U, lbase, acc);
    row_lds<3, 3>(U, lbase, acc);
    row_lds<3, 4>(U, lbase, acc);
    row_lds<3, 5>(U, lbase, acc);
    row_lds<3, 6>(U, lbase, acc);
    row_lds<2, 7>(U, lbase, acc);
    row_lds<1, 8>(U, lbase, acc);
    row_lds<0, 9>(U, lbase, acc);

    // ---- out = am * acc  (acc already contains u/am at the dq==0 row) ----
    const int ybase = gy0 + 16 * wid + ly0;
    #pragma unroll
    for (int k = 0; k < 4; ++k) {
        const int Yo = ybase + 2 * k;
        float4 o;
        o.x = U.am * acc[k][0];
        o.y = U.am * acc[k][1];
        o.z = U.am * acc[k][2];
        o.w = U.am * acc[k][3];
        *reinterpret_cast<float4*>(q + (size_t)Yo * W + gx0 + x0) = o;
    }
}

extern "C" void kernel_launch(void* const* d_in, const int* in_sizes, int n_in,
                              void* d_out, int out_size, void* d_ws, size_t ws_size,
                              hipStream_t stream) {
    const float* u     = (const float*)d_in[0];
    const float* alpha = (const float*)d_in[1];
    const float* beta  = (const float*)d_in[2];
    const float* ax    = (const float*)d_in[3];
    const float* ay    = (const float*)d_in[4];
    const float* es    = (const float*)d_in[5];
    float* out = (float*)d_out;

    int nimg = in_sizes[0] / IMG;            // 64 images
    dim3 block(256);
    dim3 grid((unsigned)(nimg * 64));        // 8x8 tiles of 64x64 per image
    fused_v17<<<grid, block, 0, stream>>>(u, out, alpha, beta, ax, ay, es);
}